// Round 12
// baseline (736.175 us; speedup 1.0000x reference)
//
#include <hip/hip_runtime.h>

// SJModel: 3x3 SAME conv (fp32, no bias) + 8-step LIF (tau=2, hard reset, v_th=1)
// x[T=8][B=16][Cin=64][H=64][W=64], W[Cout=64][Cin=64][3][3]
// out = spikes [T][B][Cout=64][H][W] fp32 (0/1)
//
// R12: R9 + TB 2->4. Per ci: 16 independent center-row loads issue upfront,
// then 1152 FMA-cycles -- halves the per-ci stall fraction vs TB=2. Each
// weight float4 now feeds 576 FMAs. LIF applied tt=0..3 sequentially;
// per-output fmaf order (ci->kh->kw) unchanged => bitwise-same spikes.

#define T_STEPS 8
#define B_SZ    16
#define CIN     64
#define COUT    64
#define H_SZ    64
#define W_SZ    64
#define HW      (H_SZ * W_SZ)
#define CO_BLK  8
#define NCB     (COUT / CO_BLK)   // 8 co-chunks
#define PX      2                 // adjacent h-rows per thread
#define TB      4                 // time steps blocked per conv pass

// W[co][ci][kh][kw] -> wt[cb][ci][kh][kw][j]
__global__ void wt_transpose(const float* __restrict__ W, float* __restrict__ wt) {
    int idx = blockIdx.x * blockDim.x + threadIdx.x;
    if (idx >= COUT * CIN * 9) return;
    int kw = idx % 3;
    int kh = (idx / 3) % 3;
    int ci = (idx / 9) % CIN;
    int co = idx / (9 * CIN);
    int cb = co / CO_BLK, j = co % CO_BLK;
    wt[(((size_t)(cb * CIN + ci) * 3 + kh) * 3 + kw) * CO_BLK + j] = W[idx];
}

__global__ void __launch_bounds__(256, 3)
lif_conv(const float* __restrict__ x, const float* __restrict__ wt,
         float* __restrict__ out) {
    const int w  = threadIdx.x;              // 0..63, lane = W dim (coalesced)
    const int ty = threadIdx.y;              // 0..3 (wave-uniform)
    const int h0 = blockIdx.x * 8 + ty * 2;  // thread owns rows h0, h0+1
    const int b  = blockIdx.y;               // 0..15
    const int cb = blockIdx.z;               // 0..7 co-chunk

    float v[PX][CO_BLK];
#pragma unroll
    for (int p = 0; p < PX; ++p)
#pragma unroll
        for (int j = 0; j < CO_BLK; ++j) v[p][j] = 0.f;

    const bool wm0 = (w > 0), wm2 = (w < W_SZ - 1);
    const bool hvT = (h0 > 0);             // input row h0-1 valid (wave-uniform)
    const bool hvB = (h0 + 2 < H_SZ);      // input row h0+2 valid (wave-uniform)

    const float* wcb = wt + (size_t)cb * CIN * 9 * CO_BLK;

    for (int t = 0; t < T_STEPS; t += TB) {
        const float* xt[TB];
#pragma unroll
        for (int tt = 0; tt < TB; ++tt)
            xt[tt] = x + (size_t)((t + tt) * B_SZ + b) * CIN * HW + h0 * W_SZ + w;

        float acc[TB][PX][CO_BLK];
#pragma unroll
        for (int tt = 0; tt < TB; ++tt)
#pragma unroll
            for (int p = 0; p < PX; ++p)
#pragma unroll
                for (int j = 0; j < CO_BLK; ++j) acc[tt][p][j] = 0.f;

        for (int ci = 0; ci < CIN; ++ci) {
            // TB time-planes x 4 center rows (h0-1..h0+2); halo cols via shuffle
            float c[TB][PX + 2];
#pragma unroll
            for (int tt = 0; tt < TB; ++tt) {
                const float* xb = xt[tt] + ci * HW;
                c[tt][0] = hvT ? xb[-W_SZ]    : 0.f;
                c[tt][1] =       xb[0];
                c[tt][2] =       xb[W_SZ];
                c[tt][3] = hvB ? xb[2 * W_SZ] : 0.f;
            }
            float xr[TB][PX + 2][3];
#pragma unroll
            for (int tt = 0; tt < TB; ++tt) {
#pragma unroll
                for (int r = 0; r < PX + 2; ++r) {
                    float lu = __shfl_up(c[tt][r], 1);    // lane w <- w-1
                    float rd = __shfl_down(c[tt][r], 1);  // lane w <- w+1
                    xr[tt][r][0] = wm0 ? lu : 0.f;        // x[w-1] (0 at w=0)
                    xr[tt][r][1] = c[tt][r];
                    xr[tt][r][2] = wm2 ? rd : 0.f;        // x[w+1] (0 at w=63)
                }
            }

            const float* wci = wcb + (size_t)ci * 9 * CO_BLK;
#pragma unroll
            for (int kh = 0; kh < 3; ++kh) {
                const float4* q = (const float4*)(wci + kh * 3 * CO_BLK);
                const float4 q00 = q[0], q01 = q[1];   // kw=0, j 0-3 / 4-7
                const float4 q10 = q[2], q11 = q[3];   // kw=1
                const float4 q20 = q[4], q21 = q[5];   // kw=2
#pragma unroll
                for (int tt = 0; tt < TB; ++tt) {
#pragma unroll
                    for (int p = 0; p < PX; ++p) {
                        const float x0 = xr[tt][p + kh][0];
                        const float x1 = xr[tt][p + kh][1];
                        const float x2 = xr[tt][p + kh][2];
                        float* a = acc[tt][p];
                        a[0] = fmaf(x0, q00.x, a[0]);
                        a[1] = fmaf(x0, q00.y, a[1]);
                        a[2] = fmaf(x0, q00.z, a[2]);
                        a[3] = fmaf(x0, q00.w, a[3]);
                        a[4] = fmaf(x0, q01.x, a[4]);
                        a[5] = fmaf(x0, q01.y, a[5]);
                        a[6] = fmaf(x0, q01.z, a[6]);
                        a[7] = fmaf(x0, q01.w, a[7]);
                        a[0] = fmaf(x1, q10.x, a[0]);
                        a[1] = fmaf(x1, q10.y, a[1]);
                        a[2] = fmaf(x1, q10.z, a[2]);
                        a[3] = fmaf(x1, q10.w, a[3]);
                        a[4] = fmaf(x1, q11.x, a[4]);
                        a[5] = fmaf(x1, q11.y, a[5]);
                        a[6] = fmaf(x1, q11.z, a[6]);
                        a[7] = fmaf(x1, q11.w, a[7]);
                        a[0] = fmaf(x2, q20.x, a[0]);
                        a[1] = fmaf(x2, q20.y, a[1]);
                        a[2] = fmaf(x2, q20.z, a[2]);
                        a[3] = fmaf(x2, q20.w, a[3]);
                        a[4] = fmaf(x2, q21.x, a[4]);
                        a[5] = fmaf(x2, q21.y, a[5]);
                        a[6] = fmaf(x2, q21.z, a[6]);
                        a[7] = fmaf(x2, q21.w, a[7]);
                    }
                }
            }
        }

        // LIF for tt=0..3 sequentially (np op order); nontemporal stores
#pragma unroll
        for (int tt = 0; tt < TB; ++tt) {
#pragma unroll
            for (int p = 0; p < PX; ++p) {
                size_t obase = ((size_t)((t + tt) * B_SZ + b) * COUT + cb * CO_BLK) * HW
                             + (size_t)(h0 + p) * W_SZ + w;
#pragma unroll
                for (int j = 0; j < CO_BLK; ++j) {
                    float vv = v[p][j];
                    vv = vv + (acc[tt][p][j] - vv) * 0.5f;   // charge: v + (z-v)/2
                    float s = (vv >= 1.0f) ? 1.f : 0.f;      // fire
                    vv = (vv >= 1.0f) ? 0.f : vv;            // hard reset
                    v[p][j] = vv;
                    __builtin_nontemporal_store(s, &out[obase + (size_t)j * HW]);
                }
            }
        }
    }
}

extern "C" void kernel_launch(void* const* d_in, const int* in_sizes, int n_in,
                              void* d_out, int out_size, void* d_ws, size_t ws_size,
                              hipStream_t stream) {
    const float* x  = (const float*)d_in[0];
    const float* W  = (const float*)d_in[1];
    float* out = (float*)d_out;
    float* wt  = (float*)d_ws;   // 64*64*9*4 = 147456 B scratch

    wt_transpose<<<dim3((COUT * CIN * 9 + 255) / 256), dim3(256), 0, stream>>>(W, wt);
    lif_conv<<<dim3(8, 16, 8), dim3(64, 4, 1), 0, stream>>>(x, wt, out);
}

// Round 15
// 655.754 us; speedup vs baseline: 1.1226x; 1.1226x over previous
//
#include <hip/hip_runtime.h>

// SJModel: 3x3 SAME conv (fp32, no bias) + 8-step LIF (tau=2, hard reset, v_th=1)
// x[T=8][B=16][Cin=64][H=64][W=64], W[Cout=64][Cin=64][3][3]
// out = spikes [T][B][Cout=64][H][W] fp32 (0/1)
//
// R13 (3rd submit; broker timeouts, kernel never ran): R11 (TB=2,
// shuffle-halo, 533us) + explicit 1-deep ci software pipeline: issue ci+1's
// 8 independent center-row loads BEFORE ci's FMA burst so their VMEM latency
// hides under 576 FMA-cycles. Branchless (index clamp; final redundant load
// unused). Consumed values and per-output fmaf order (ci->kh->kw) identical
// to R11 => bitwise-same spikes.

#define T_STEPS 8
#define B_SZ    16
#define CIN     64
#define COUT    64
#define H_SZ    64
#define W_SZ    64
#define HW      (H_SZ * W_SZ)
#define CO_BLK  8
#define NCB     (COUT / CO_BLK)   // 8 co-chunks
#define PX      2                 // adjacent h-rows per thread
#define TB      2                 // time steps blocked per conv pass

// W[co][ci][kh][kw] -> wt[cb][ci][kh][kw][j]
__global__ void wt_transpose(const float* __restrict__ W, float* __restrict__ wt) {
    int idx = blockIdx.x * blockDim.x + threadIdx.x;
    if (idx >= COUT * CIN * 9) return;
    int kw = idx % 3;
    int kh = (idx / 3) % 3;
    int ci = (idx / 9) % CIN;
    int co = idx / (9 * CIN);
    int cb = co / CO_BLK, j = co % CO_BLK;
    wt[(((size_t)(cb * CIN + ci) * 3 + kh) * 3 + kw) * CO_BLK + j] = W[idx];
}

__global__ void __launch_bounds__(256, 3)
lif_conv(const float* __restrict__ x, const float* __restrict__ wt,
         float* __restrict__ out) {
    const int w  = threadIdx.x;              // 0..63, lane = W dim (coalesced)
    const int ty = threadIdx.y;              // 0..3 (wave-uniform)
    const int h0 = blockIdx.x * 8 + ty * 2;  // thread owns rows h0, h0+1
    const int b  = blockIdx.y;               // 0..15
    const int cb = blockIdx.z;               // 0..7 co-chunk

    float v[PX][CO_BLK];
#pragma unroll
    for (int p = 0; p < PX; ++p)
#pragma unroll
        for (int j = 0; j < CO_BLK; ++j) v[p][j] = 0.f;

    const bool wm0 = (w > 0), wm2 = (w < W_SZ - 1);
    const bool hvT = (h0 > 0);             // input row h0-1 valid (wave-uniform)
    const bool hvB = (h0 + 2 < H_SZ);      // input row h0+2 valid (wave-uniform)

    const float* wcb = wt + (size_t)cb * CIN * 9 * CO_BLK;

    for (int t = 0; t < T_STEPS; t += TB) {
        const float* xt0 = x + (size_t)(t * B_SZ + b) * CIN * HW + h0 * W_SZ + w;
        const float* xt1 = xt0 + (size_t)B_SZ * CIN * HW;   // t+1 plane

        float acc[TB][PX][CO_BLK];
#pragma unroll
        for (int tt = 0; tt < TB; ++tt)
#pragma unroll
            for (int p = 0; p < PX; ++p)
#pragma unroll
                for (int j = 0; j < CO_BLK; ++j) acc[tt][p][j] = 0.f;

        // prologue: load ci=0 center rows (2 planes x 4 rows)
        float cb0[TB][PX + 2];
#pragma unroll
        for (int tt = 0; tt < TB; ++tt) {
            const float* xb = (tt == 0 ? xt0 : xt1);
            cb0[tt][0] = hvT ? xb[-W_SZ]    : 0.f;
            cb0[tt][1] =       xb[0];
            cb0[tt][2] =       xb[W_SZ];
            cb0[tt][3] = hvB ? xb[2 * W_SZ] : 0.f;
        }

        for (int ci = 0; ci < CIN; ++ci) {
            // issue NEXT ci's 8 independent loads first (clamped; last is unused)
            const int cin = (ci + 1 < CIN) ? (ci + 1) : (CIN - 1);
            float cnx[TB][PX + 2];
#pragma unroll
            for (int tt = 0; tt < TB; ++tt) {
                const float* xb = (tt == 0 ? xt0 : xt1) + cin * HW;
                cnx[tt][0] = hvT ? xb[-W_SZ]    : 0.f;
                cnx[tt][1] =       xb[0];
                cnx[tt][2] =       xb[W_SZ];
                cnx[tt][3] = hvB ? xb[2 * W_SZ] : 0.f;
            }

            // halo cols for CURRENT ci via cross-lane shuffle
            float xr[TB][PX + 2][3];
#pragma unroll
            for (int tt = 0; tt < TB; ++tt) {
#pragma unroll
                for (int r = 0; r < PX + 2; ++r) {
                    float lu = __shfl_up(cb0[tt][r], 1);    // lane w <- w-1
                    float rd = __shfl_down(cb0[tt][r], 1);  // lane w <- w+1
                    xr[tt][r][0] = wm0 ? lu : 0.f;          // x[w-1]
                    xr[tt][r][1] = cb0[tt][r];
                    xr[tt][r][2] = wm2 ? rd : 0.f;          // x[w+1]
                }
            }

            const float* wci = wcb + (size_t)ci * 9 * CO_BLK;
#pragma unroll
            for (int kh = 0; kh < 3; ++kh) {
                const float4* q = (const float4*)(wci + kh * 3 * CO_BLK);
                const float4 q00 = q[0], q01 = q[1];   // kw=0, j 0-3 / 4-7
                const float4 q10 = q[2], q11 = q[3];   // kw=1
                const float4 q20 = q[4], q21 = q[5];   // kw=2
#pragma unroll
                for (int tt = 0; tt < TB; ++tt) {
#pragma unroll
                    for (int p = 0; p < PX; ++p) {
                        const float x0 = xr[tt][p + kh][0];
                        const float x1 = xr[tt][p + kh][1];
                        const float x2 = xr[tt][p + kh][2];
                        float* a = acc[tt][p];
                        a[0] = fmaf(x0, q00.x, a[0]);
                        a[1] = fmaf(x0, q00.y, a[1]);
                        a[2] = fmaf(x0, q00.z, a[2]);
                        a[3] = fmaf(x0, q00.w, a[3]);
                        a[4] = fmaf(x0, q01.x, a[4]);
                        a[5] = fmaf(x0, q01.y, a[5]);
                        a[6] = fmaf(x0, q01.z, a[6]);
                        a[7] = fmaf(x0, q01.w, a[7]);
                        a[0] = fmaf(x1, q10.x, a[0]);
                        a[1] = fmaf(x1, q10.y, a[1]);
                        a[2] = fmaf(x1, q10.z, a[2]);
                        a[3] = fmaf(x1, q10.w, a[3]);
                        a[4] = fmaf(x1, q11.x, a[4]);
                        a[5] = fmaf(x1, q11.y, a[5]);
                        a[6] = fmaf(x1, q11.z, a[6]);
                        a[7] = fmaf(x1, q11.w, a[7]);
                        a[0] = fmaf(x2, q20.x, a[0]);
                        a[1] = fmaf(x2, q20.y, a[1]);
                        a[2] = fmaf(x2, q20.z, a[2]);
                        a[3] = fmaf(x2, q20.w, a[3]);
                        a[4] = fmaf(x2, q21.x, a[4]);
                        a[5] = fmaf(x2, q21.y, a[5]);
                        a[6] = fmaf(x2, q21.z, a[6]);
                        a[7] = fmaf(x2, q21.w, a[7]);
                    }
                }
            }

            // rotate pipeline
#pragma unroll
            for (int tt = 0; tt < TB; ++tt)
#pragma unroll
                for (int r = 0; r < PX + 2; ++r) cb0[tt][r] = cnx[tt][r];
        }

        // LIF for t then t+1 (sequential in tt), np op order; nontemporal stores
#pragma unroll
        for (int tt = 0; tt < TB; ++tt) {
#pragma unroll
            for (int p = 0; p < PX; ++p) {
                size_t obase = ((size_t)((t + tt) * B_SZ + b) * COUT + cb * CO_BLK) * HW
                             + (size_t)(h0 + p) * W_SZ + w;
#pragma unroll
                for (int j = 0; j < CO_BLK; ++j) {
                    float vv = v[p][j];
                    vv = vv + (acc[tt][p][j] - vv) * 0.5f;   // charge: v + (z-v)/2
                    float s = (vv >= 1.0f) ? 1.f : 0.f;      // fire
                    vv = (vv >= 1.0f) ? 0.f : vv;            // hard reset
                    v[p][j] = vv;
                    __builtin_nontemporal_store(s, &out[obase + (size_t)j * HW]);
                }
            }
        }
    }
}

extern "C" void kernel_launch(void* const* d_in, const int* in_sizes, int n_in,
                              void* d_out, int out_size, void* d_ws, size_t ws_size,
                              hipStream_t stream) {
    const float* x  = (const float*)d_in[0];
    const float* W  = (const float*)d_in[1];
    float* out = (float*)d_out;
    float* wt  = (float*)d_ws;   // 64*64*9*4 = 147456 B scratch

    wt_transpose<<<dim3((COUT * CIN * 9 + 255) / 256), dim3(256), 0, stream>>>(W, wt);
    lif_conv<<<dim3(8, 16, 8), dim3(64, 4, 1), 0, stream>>>(x, wt, out);
}